// Round 6
// baseline (635.840 us; speedup 1.0000x reference)
//
#include <hip/hip_runtime.h>

// SNN with "swapped outputs" bug: stored state = spike (binary), forwarded
// value = membrane. reset = (spk_prev > 1) == 0 always -> mem = cur + 0.9*spk_prev.
// Constant input -> spike patterns fixate: mem0 const t>=1, mem1 t>=2, out t>=3.
// GEMM0 (256x2048,K=1024); GEMM1 over {mem0(0),mem0(inf)} (M=512,K=2048);
// GEMM2 over {mem1(0),mem1(1),mem1(inf)} (M=768,N=1024,K=2048); broadcast t>=3.
//
// bf16 MFMA GEMM + exact f64 fixup of borderline elements (|mem-1|<0.04 or
// |mem-0.1|<0.04). Round-5 lesson: ballot-while fixup is straggler-bound
// (115us). Round 6: two-phase fixup — compact bad indices (wave prefix-sum +
// one atomicAdd/wave), then a fixed-grid kernel with round-robin wave
// assignment. GEMM/LIF numerics byte-identical to the passing round-5 kernel.

typedef unsigned short ushort_t;
typedef __attribute__((ext_vector_type(8))) short bf16x8;
typedef __attribute__((ext_vector_type(4))) float f32x4;

#define GKT 64
#define GLD (GKT + 8)   // 72-short row stride: 144B, 16B-aligned, 2-way frag reads
#define DELTA 0.04f

__device__ inline ushort_t f2bf(float f) {       // RNE f32 -> bf16
    unsigned u = __float_as_uint(f);
    u += 0x7FFFu + ((u >> 16) & 1u);
    return (ushort_t)(u >> 16);
}
__device__ inline float4 ld4(const float* p) { return *reinterpret_cast<const float4*>(p); }

// ---------------- bf16 GEMM: C = A @ W^T + bias, tile 64x64, 4 waves ----------------
__global__ __launch_bounds__(256, 1) void gemm_bf16(
    const ushort_t* __restrict__ A,   // [M,K] bf16
    const ushort_t* __restrict__ W,   // [N,K] bf16
    const float* __restrict__ bias,   // [N]
    float* __restrict__ C,            // [M,N] f32
    int N, int K)
{
    __shared__ ushort_t As[64 * GLD];
    __shared__ ushort_t Ws[64 * GLD];

    const int tid  = threadIdx.x;
    const int row0 = blockIdx.y * 64;
    const int col0 = blockIdx.x * 64;
    const int itr  = tid >> 3;          // staging row 0..31 (item0), +32 (item1)
    const int itk  = (tid & 7) * 8;     // k-chunk of 8 bf16

    const ushort_t* Ap = A + (size_t)(row0 + itr) * K + itk;
    const ushort_t* Wp = W + (size_t)(col0 + itr) * K + itk;
    const size_t r32 = (size_t)32 * K;

    uint4 pa0, pa1, pw0, pw1;
    auto load = [&](int k0) {
        pa0 = *reinterpret_cast<const uint4*>(Ap + k0);
        pa1 = *reinterpret_cast<const uint4*>(Ap + r32 + k0);
        pw0 = *reinterpret_cast<const uint4*>(Wp + k0);
        pw1 = *reinterpret_cast<const uint4*>(Wp + r32 + k0);
    };
    const int s0 = itr * GLD + itk, s1 = s0 + 32 * GLD;
    auto store = [&]() {
        *reinterpret_cast<uint4*>(&As[s0]) = pa0;
        *reinterpret_cast<uint4*>(&As[s1]) = pa1;
        *reinterpret_cast<uint4*>(&Ws[s0]) = pw0;
        *reinterpret_cast<uint4*>(&Ws[s1]) = pw1;
    };

    // wave (wr,wc) owns 32x32; lane frags per m89-verified layouts
    const int lane = tid & 63;
    const int l15  = lane & 15;
    const int kh   = lane >> 4;         // 0..3
    const int wid  = tid >> 6;
    const int wr   = wid >> 1, wc = wid & 1;

    const ushort_t* aB[2];
    const ushort_t* bB[2];
#pragma unroll
    for (int i = 0; i < 2; ++i) {
        aB[i] = &As[(wr * 32 + i * 16 + l15) * GLD + kh * 8];
        bB[i] = &Ws[(wc * 32 + i * 16 + l15) * GLD + kh * 8];
    }

    f32x4 acc[2][2] = {};
    const int NT = K / GKT;

    load(0);
    for (int kt = 0; kt < NT; ++kt) {
        __syncthreads();
        store();
        __syncthreads();
        if (kt + 1 < NT) load((kt + 1) * GKT);
#pragma unroll
        for (int ks = 0; ks < GKT; ks += 32) {
            bf16x8 a0 = *reinterpret_cast<const bf16x8*>(aB[0] + ks);
            bf16x8 a1 = *reinterpret_cast<const bf16x8*>(aB[1] + ks);
            bf16x8 b0 = *reinterpret_cast<const bf16x8*>(bB[0] + ks);
            bf16x8 b1 = *reinterpret_cast<const bf16x8*>(bB[1] + ks);
            acc[0][0] = __builtin_amdgcn_mfma_f32_16x16x32_bf16(a0, b0, acc[0][0], 0, 0, 0);
            acc[0][1] = __builtin_amdgcn_mfma_f32_16x16x32_bf16(a0, b1, acc[0][1], 0, 0, 0);
            acc[1][0] = __builtin_amdgcn_mfma_f32_16x16x32_bf16(a1, b0, acc[1][0], 0, 0, 0);
            acc[1][1] = __builtin_amdgcn_mfma_f32_16x16x32_bf16(a1, b1, acc[1][1], 0, 0, 0);
        }
    }

    // C/D layout (m89): col = lane&15, row = (lane>>4)*4 + reg
#pragma unroll
    for (int bn = 0; bn < 2; ++bn) {
        const int col = col0 + wc * 32 + bn * 16 + l15;
        const float bv = bias[col];
#pragma unroll
        for (int am = 0; am < 2; ++am) {
            const int rb = row0 + wr * 32 + am * 16 + kh * 4;
#pragma unroll
            for (int i = 0; i < 4; ++i)
                C[(size_t)(rb + i) * N + col] = acc[am][bn][i] + bv;
        }
    }
}

// ---------------- f32 -> bf16 conversion (vectorized) ----------------
__global__ __launch_bounds__(256) void cvt_bf16(const float4* __restrict__ src,
                                                ushort4* __restrict__ dst, int n4)
{
    int i = blockIdx.x * 256 + threadIdx.x;
    if (i < n4) {
        float4 v = src[i];
        ushort4 o;
        o.x = f2bf(v.x); o.y = f2bf(v.y); o.z = f2bf(v.z); o.w = f2bf(v.w);
        dst[i] = o;
    }
}

// ---------------- fixup phase 0: zero the 3 counters ----------------
__global__ __launch_bounds__(64) void zero_counters(int* __restrict__ ctrs)
{
    if (threadIdx.x < 3) ctrs[threadIdx.x * 16] = 0;
}

// ---------------- fixup phase 1: compact borderline indices ----------------
__global__ __launch_bounds__(256) void scan_bad(const float4* __restrict__ C, int n4,
                                                int* __restrict__ list,
                                                int* __restrict__ counter)
{
    const int i = blockIdx.x * 256 + threadIdx.x;
    const int lane = threadIdx.x & 63;
    int lc = 0;
    int loc[4];
    if (i < n4) {
        float4 v = C[i];
        float vv[4] = {v.x, v.y, v.z, v.w};
#pragma unroll
        for (int c = 0; c < 4; ++c) {
            if ((fabsf(vv[c] - 1.0f) < DELTA) || (fabsf(vv[c] - 0.1f) < DELTA))
                loc[lc++] = i * 4 + c;
        }
    }
    int inc = lc;                       // wave inclusive prefix sum
#pragma unroll
    for (int off = 1; off < 64; off <<= 1) {
        int t = __shfl_up(inc, off);
        if (lane >= off) inc += t;
    }
    const int total = __shfl(inc, 63);
    int base = 0;
    if (lane == 63 && total) base = atomicAdd(counter, total);
    base = __shfl(base, 63);
    const int excl = inc - lc;
    for (int j = 0; j < lc; ++j) list[base + excl + j] = loc[j];
}

// ---------------- fixup phase 2: exact f64 dot per bad element ----------------
// MODE 0: A row = P (x).  MODE 1: A1 recon from C0.  MODE 2: A2 recon from C1.
template <int MODE>
__global__ __launch_bounds__(256) void fixup2_kernel(
    float* __restrict__ C, const float* __restrict__ P,
    const float* __restrict__ Wf, const float* __restrict__ bias,
    const int* __restrict__ list, const int* __restrict__ counter,
    int logN, int K)
{
    const int lane = threadIdx.x & 63;
    const int wave = (blockIdx.x * 256 + threadIdx.x) >> 6;
    const int nw   = gridDim.x * (256 / 64);
    const int nbad = *counter;

    for (int e = wave; e < nbad; e += nw) {
        const int idx = list[e];
        const int rr = idx >> logN;
        const int cc = idx & ((1 << logN) - 1);
        const float* wrow = Wf + (size_t)cc * K;
        double p = 0.0;
        for (int k = lane * 4; k < K; k += 256) {
            const float4 w4 = ld4(wrow + k);
            float4 a4;
            if (MODE == 0) {
                a4 = ld4(P + (size_t)rr * K + k);
            } else if (MODE == 1) {
                if (rr < 256) a4 = ld4(P + (size_t)rr * K + k);
                else {
                    float4 c0 = ld4(P + (size_t)(rr - 256) * K + k);
                    a4.x = c0.x + ((c0.x > 1.0f) ? 0.9f : 0.0f);
                    a4.y = c0.y + ((c0.y > 1.0f) ? 0.9f : 0.0f);
                    a4.z = c0.z + ((c0.z > 1.0f) ? 0.9f : 0.0f);
                    a4.w = c0.w + ((c0.w > 1.0f) ? 0.9f : 0.0f);
                }
            } else {
                const int i0 = rr & 255, pl = rr >> 8;
                float4 c0 = ld4(P + (size_t)i0 * K + k);
                if (pl == 0) a4 = c0;
                else {
                    float4 ci = ld4(P + (size_t)(i0 + 256) * K + k);
                    float4 m1;
                    m1.x = ci.x + ((c0.x > 1.0f) ? 0.9f : 0.0f);
                    m1.y = ci.y + ((c0.y > 1.0f) ? 0.9f : 0.0f);
                    m1.z = ci.z + ((c0.z > 1.0f) ? 0.9f : 0.0f);
                    m1.w = ci.w + ((c0.w > 1.0f) ? 0.9f : 0.0f);
                    if (pl == 1) a4 = m1;
                    else {
                        a4.x = ci.x + ((m1.x > 1.0f) ? 0.9f : 0.0f);
                        a4.y = ci.y + ((m1.y > 1.0f) ? 0.9f : 0.0f);
                        a4.z = ci.z + ((m1.z > 1.0f) ? 0.9f : 0.0f);
                        a4.w = ci.w + ((m1.w > 1.0f) ? 0.9f : 0.0f);
                    }
                }
            }
            p = fma((double)a4.x, (double)w4.x, p);
            p = fma((double)a4.y, (double)w4.y, p);
            p = fma((double)a4.z, (double)w4.z, p);
            p = fma((double)a4.w, (double)w4.w, p);
        }
#pragma unroll
        for (int off = 32; off; off >>= 1) p += __shfl_down(p, off);
        if (lane == 0) C[idx] = (float)(p + (double)bias[cc]);
    }
}

// ---------------- LIF kernels (f32 exact; also emit bf16 A for next GEMM) ----------------
__global__ __launch_bounds__(256) void lif0_kernel(const float4* __restrict__ C0,
                                                   ushort4* __restrict__ A1b, int n4)
{
    int i = blockIdx.x * 256 + threadIdx.x;
    if (i < n4) {
        float4 cv = C0[i];
        ushort4 p0, p1;
        p0.x = f2bf(cv.x); p0.y = f2bf(cv.y); p0.z = f2bf(cv.z); p0.w = f2bf(cv.w);
        float4 mi;
        mi.x = cv.x + ((cv.x > 1.0f) ? 0.9f : 0.0f);
        mi.y = cv.y + ((cv.y > 1.0f) ? 0.9f : 0.0f);
        mi.z = cv.z + ((cv.z > 1.0f) ? 0.9f : 0.0f);
        mi.w = cv.w + ((cv.w > 1.0f) ? 0.9f : 0.0f);
        p1.x = f2bf(mi.x); p1.y = f2bf(mi.y); p1.z = f2bf(mi.z); p1.w = f2bf(mi.w);
        A1b[i] = p0; A1b[n4 + i] = p1;
    }
}

__global__ __launch_bounds__(256) void lif1_kernel(const float4* __restrict__ C1,
                                                   ushort4* __restrict__ A2b, int n4)
{
    int i = blockIdx.x * 256 + threadIdx.x;
    if (i < n4) {
        float4 c0 = C1[i], ci = C1[n4 + i];
        float4 m1, m2;
        m1.x = ci.x + ((c0.x > 1.0f) ? 0.9f : 0.0f);
        m1.y = ci.y + ((c0.y > 1.0f) ? 0.9f : 0.0f);
        m1.z = ci.z + ((c0.z > 1.0f) ? 0.9f : 0.0f);
        m1.w = ci.w + ((c0.w > 1.0f) ? 0.9f : 0.0f);
        m2.x = ci.x + ((m1.x > 1.0f) ? 0.9f : 0.0f);
        m2.y = ci.y + ((m1.y > 1.0f) ? 0.9f : 0.0f);
        m2.z = ci.z + ((m1.z > 1.0f) ? 0.9f : 0.0f);
        m2.w = ci.w + ((m1.w > 1.0f) ? 0.9f : 0.0f);
        ushort4 p0, p1, p2;
        p0.x = f2bf(c0.x); p0.y = f2bf(c0.y); p0.z = f2bf(c0.z); p0.w = f2bf(c0.w);
        p1.x = f2bf(m1.x); p1.y = f2bf(m1.y); p1.z = f2bf(m1.z); p1.w = f2bf(m1.w);
        p2.x = f2bf(m2.x); p2.y = f2bf(m2.y); p2.z = f2bf(m2.z); p2.w = f2bf(m2.w);
        A2b[i] = p0; A2b[n4 + i] = p1; A2b[2 * n4 + i] = p2;
    }
}

// Final layer + broadcast; grid.y covers 4 time-slices each.
__global__ __launch_bounds__(256) void lif2_bcast(const float4* __restrict__ c2,
                                                  float4* __restrict__ out, int n4)
{
    int i = blockIdx.x * 256 + threadIdx.x;
    if (i >= n4) return;
    float4 c0 = c2[i], c1 = c2[n4 + i], ci = c2[2 * n4 + i];
    float4 m0 = c0, m1, m2, m3;
    m1.x = c1.x + ((m0.x > 1.0f) ? 0.9f : 0.0f);
    m1.y = c1.y + ((m0.y > 1.0f) ? 0.9f : 0.0f);
    m1.z = c1.z + ((m0.z > 1.0f) ? 0.9f : 0.0f);
    m1.w = c1.w + ((m0.w > 1.0f) ? 0.9f : 0.0f);
    m2.x = ci.x + ((m1.x > 1.0f) ? 0.9f : 0.0f);
    m2.y = ci.y + ((m1.y > 1.0f) ? 0.9f : 0.0f);
    m2.z = ci.z + ((m1.z > 1.0f) ? 0.9f : 0.0f);
    m2.w = ci.w + ((m1.w > 1.0f) ? 0.9f : 0.0f);
    m3.x = ci.x + ((m2.x > 1.0f) ? 0.9f : 0.0f);
    m3.y = ci.y + ((m2.y > 1.0f) ? 0.9f : 0.0f);
    m3.z = ci.z + ((m2.z > 1.0f) ? 0.9f : 0.0f);
    m3.w = ci.w + ((m2.w > 1.0f) ? 0.9f : 0.0f);
    int t0 = blockIdx.y * 4;
#pragma unroll
    for (int j = 0; j < 4; ++j) {
        int t = t0 + j;
        float4 v = (t == 0) ? m0 : (t == 1) ? m1 : (t == 2) ? m2 : m3;
        out[(size_t)t * n4 + i] = v;
    }
}

extern "C" void kernel_launch(void* const* d_in, const int* in_sizes, int n_in,
                              void* d_out, int out_size, void* d_ws, size_t ws_size,
                              hipStream_t stream)
{
    const float* x  = (const float*)d_in[0];  // [256,1024]
    const float* W0 = (const float*)d_in[1];  // [2048,1024]
    const float* b0 = (const float*)d_in[2];
    const float* W1 = (const float*)d_in[3];  // [2048,2048]
    const float* b1 = (const float*)d_in[4];
    const float* W2 = (const float*)d_in[5];  // [1024,2048]
    const float* b2 = (const float*)d_in[6];
    float* out = (float*)d_out;
    float* ws  = (float*)d_ws;

    // ws (floats): C0 @0 (512K) | C1 @512K (1M) | C2 @1.5M (768K) |
    //              xb @2359296 | A1b @2490368 | A2b @3014656  (bf16 in float slots)
    float*    C0  = ws;
    float*    C1  = ws + 524288;
    float*    C2  = ws + 1572864;
    ushort_t* xb  = (ushort_t*)(ws + 2359296);
    ushort_t* A1b = (ushort_t*)(ws + 2490368);
    ushort_t* A2b = (ushort_t*)(ws + 3014656);
    // d_out scratch (all overwritten by lif2_bcast at the end):
    ushort_t* Wb0 = (ushort_t*)(out);              // 2M bf16
    ushort_t* Wb1 = (ushort_t*)(out + 1048576);    // 4M bf16
    ushort_t* Wb2 = (ushort_t*)(out + 3145728);    // 2M bf16
    int* ctrs  = (int*)(out + 4194304);            // 3 counters, 64B apart
    int* list0 = (int*)(out + 4456448);            // cap 512K
    int* list1 = (int*)(out + 5242880);            // cap 1M
    int* list2 = (int*)(out + 6291456);            // cap 768K

    dim3 blk(256);

    zero_counters<<<dim3(1), dim3(64), 0, stream>>>(ctrs);
    cvt_bf16<<<dim3(256),  blk, 0, stream>>>((const float4*)x,  (ushort4*)xb,  65536);
    cvt_bf16<<<dim3(2048), blk, 0, stream>>>((const float4*)W0, (ushort4*)Wb0, 524288);
    cvt_bf16<<<dim3(4096), blk, 0, stream>>>((const float4*)W1, (ushort4*)Wb1, 1048576);
    cvt_bf16<<<dim3(2048), blk, 0, stream>>>((const float4*)W2, (ushort4*)Wb2, 524288);

    // GEMM0: cur0 = x @ W0^T + b0  [256,2048]
    gemm_bf16<<<dim3(32, 4), blk, 0, stream>>>(xb, Wb0, b0, C0, 2048, 1024);
    scan_bad<<<dim3(512), blk, 0, stream>>>((const float4*)C0, 131072, list0, ctrs + 0);
    fixup2_kernel<0><<<dim3(512), blk, 0, stream>>>(C0, x, W0, b0, list0, ctrs + 0, 11, 1024);
    lif0_kernel<<<dim3(512), blk, 0, stream>>>((const float4*)C0, (ushort4*)A1b, 131072);

    // GEMM1: [cur1(0); cur1(inf)] [512,2048]
    gemm_bf16<<<dim3(32, 8), blk, 0, stream>>>(A1b, Wb1, b1, C1, 2048, 2048);
    scan_bad<<<dim3(1024), blk, 0, stream>>>((const float4*)C1, 262144, list1, ctrs + 16);
    fixup2_kernel<1><<<dim3(512), blk, 0, stream>>>(C1, C0, W1, b1, list1, ctrs + 16, 11, 2048);
    lif1_kernel<<<dim3(512), blk, 0, stream>>>((const float4*)C1, (ushort4*)A2b, 131072);

    // GEMM2: 3 layer-2 currents [768,1024]
    gemm_bf16<<<dim3(16, 12), blk, 0, stream>>>(A2b, Wb2, b2, C2, 1024, 2048);
    scan_bad<<<dim3(768), blk, 0, stream>>>((const float4*)C2, 196608, list2, ctrs + 32);
    fixup2_kernel<2><<<dim3(512), blk, 0, stream>>>(C2, C1, W2, b2, list2, ctrs + 32, 10, 2048);

    // layer-2 LIF + output broadcast (overwrites all of d_out incl. scratch)
    lif2_bcast<<<dim3(256, 25), blk, 0, stream>>>((const float4*)C2, (float4*)out, 65536);
}

// Round 7
// 265.672 us; speedup vs baseline: 2.3933x; 2.3933x over previous
//
#include <hip/hip_runtime.h>

// SNN with "swapped outputs" bug: stored state = spike (binary), forwarded
// value = membrane. reset = (spk_prev > 1) == 0 always -> mem = cur + 0.9*spk_prev.
// Constant input -> spike patterns fixate: mem0 const t>=1, mem1 t>=2, out t>=3.
// GEMM0 (256x2048,K=1024); GEMM1 over {mem0(0),mem0(inf)} (M=512,K=2048);
// GEMM2 over {mem1(0),mem1(1),mem1(inf)} (M=768,N=1024,K=2048); broadcast t>=3.
//
// Round-6 lesson: 22K borderline elements x 16KB = 356MB scattered fixup
// traffic. Round 7: split-bf16 GEMM — A=Ah+Al, W=Wh+Wl, compute
// Ah.Wh + Ah.Wl + Al.Wh as ONE GEMM with K'=3K (A''=[Ah|Ah|Al], W''=[Wh|Wl|Wh]).
// GEMM error ~1e-5 -> DELTA 0.04 -> 1e-3 -> ~20x fewer bad elements. f64
// fixup (exact, decision-safe, same arithmetic as all passing rounds) with
// chunked-contiguous wave assignment for locality.

typedef unsigned short ushort_t;
typedef __attribute__((ext_vector_type(8))) short bf16x8;
typedef __attribute__((ext_vector_type(4))) float f32x4;

#define GKT 64
#define GLD (GKT + 8)     // 72-short row stride: 16B-aligned, 2-way frag reads
#define SDELTA 1.0e-3f    // borderline window (split-GEMM error ~1e-5: 100x margin)

__device__ inline ushort_t f2bf(float f) {       // RNE f32 -> bf16
    unsigned u = __float_as_uint(f);
    u += 0x7FFFu + ((u >> 16) & 1u);
    return (ushort_t)(u >> 16);
}
__device__ inline float bf2f(ushort_t h) { return __uint_as_float((unsigned)h << 16); }
__device__ inline float4 ld4(const float* p) { return *reinterpret_cast<const float4*>(p); }

// ---------------- bf16 GEMM: C = A @ W^T + bias, tile 64x64, 4 waves ----------------
__global__ __launch_bounds__(256, 1) void gemm_bf16(
    const ushort_t* __restrict__ A,   // [M,K] bf16
    const ushort_t* __restrict__ W,   // [N,K] bf16
    const float* __restrict__ bias,   // [N]
    float* __restrict__ C,            // [M,N] f32
    int N, int K)
{
    __shared__ ushort_t As[64 * GLD];
    __shared__ ushort_t Ws[64 * GLD];

    const int tid  = threadIdx.x;
    const int row0 = blockIdx.y * 64;
    const int col0 = blockIdx.x * 64;
    const int itr  = tid >> 3;          // staging row 0..31 (item0), +32 (item1)
    const int itk  = (tid & 7) * 8;     // k-chunk of 8 bf16

    const ushort_t* Ap = A + (size_t)(row0 + itr) * K + itk;
    const ushort_t* Wp = W + (size_t)(col0 + itr) * K + itk;
    const size_t r32 = (size_t)32 * K;

    uint4 pa0, pa1, pw0, pw1;
    auto load = [&](int k0) {
        pa0 = *reinterpret_cast<const uint4*>(Ap + k0);
        pa1 = *reinterpret_cast<const uint4*>(Ap + r32 + k0);
        pw0 = *reinterpret_cast<const uint4*>(Wp + k0);
        pw1 = *reinterpret_cast<const uint4*>(Wp + r32 + k0);
    };
    const int s0 = itr * GLD + itk, s1 = s0 + 32 * GLD;
    auto store = [&]() {
        *reinterpret_cast<uint4*>(&As[s0]) = pa0;
        *reinterpret_cast<uint4*>(&As[s1]) = pa1;
        *reinterpret_cast<uint4*>(&Ws[s0]) = pw0;
        *reinterpret_cast<uint4*>(&Ws[s1]) = pw1;
    };

    // wave (wr,wc) owns 32x32; lane frags per m89-verified layouts
    const int lane = tid & 63;
    const int l15  = lane & 15;
    const int kh   = lane >> 4;         // 0..3
    const int wid  = tid >> 6;
    const int wr   = wid >> 1, wc = wid & 1;

    const ushort_t* aB[2];
    const ushort_t* bB[2];
#pragma unroll
    for (int i = 0; i < 2; ++i) {
        aB[i] = &As[(wr * 32 + i * 16 + l15) * GLD + kh * 8];
        bB[i] = &Ws[(wc * 32 + i * 16 + l15) * GLD + kh * 8];
    }

    f32x4 acc[2][2] = {};
    const int NT = K / GKT;

    load(0);
    for (int kt = 0; kt < NT; ++kt) {
        __syncthreads();
        store();
        __syncthreads();
        if (kt + 1 < NT) load((kt + 1) * GKT);
#pragma unroll
        for (int ks = 0; ks < GKT; ks += 32) {
            bf16x8 a0 = *reinterpret_cast<const bf16x8*>(aB[0] + ks);
            bf16x8 a1 = *reinterpret_cast<const bf16x8*>(aB[1] + ks);
            bf16x8 b0 = *reinterpret_cast<const bf16x8*>(bB[0] + ks);
            bf16x8 b1 = *reinterpret_cast<const bf16x8*>(bB[1] + ks);
            acc[0][0] = __builtin_amdgcn_mfma_f32_16x16x32_bf16(a0, b0, acc[0][0], 0, 0, 0);
            acc[0][1] = __builtin_amdgcn_mfma_f32_16x16x32_bf16(a0, b1, acc[0][1], 0, 0, 0);
            acc[1][0] = __builtin_amdgcn_mfma_f32_16x16x32_bf16(a1, b0, acc[1][0], 0, 0, 0);
            acc[1][1] = __builtin_amdgcn_mfma_f32_16x16x32_bf16(a1, b1, acc[1][1], 0, 0, 0);
        }
    }

    // C/D layout (m89): col = lane&15, row = (lane>>4)*4 + reg
#pragma unroll
    for (int bn = 0; bn < 2; ++bn) {
        const int col = col0 + wc * 32 + bn * 16 + l15;
        const float bv = bias[col];
#pragma unroll
        for (int am = 0; am < 2; ++am) {
            const int rb = row0 + wr * 32 + am * 16 + kh * 4;
#pragma unroll
            for (int i = 0; i < 4; ++i)
                C[(size_t)(rb + i) * N + col] = acc[am][bn][i] + bv;
        }
    }
}

// ---------------- split f32 -> [seg0|seg1|seg2] bf16, row width 3K ----------------
// ASIDE=1: [h|h|l] (A operand).  ASIDE=0: [h|l|h] (W operand).
template <int ASIDE>
__global__ __launch_bounds__(256) void cvt_split(const float4* __restrict__ src,
                                                 ushort_t* __restrict__ dst,
                                                 int n4, int logK)
{
    int i = blockIdx.x * 256 + threadIdx.x;
    if (i >= n4) return;
    float4 v = src[i];
    const int K = 1 << logK;
    const int e0 = i * 4;
    const int r = e0 >> logK, k = e0 & (K - 1);
    ushort_t* row = dst + (size_t)r * 3 * K;
    ushort4 h, l;
    h.x = f2bf(v.x); l.x = f2bf(v.x - bf2f(h.x));
    h.y = f2bf(v.y); l.y = f2bf(v.y - bf2f(h.y));
    h.z = f2bf(v.z); l.z = f2bf(v.z - bf2f(h.z));
    h.w = f2bf(v.w); l.w = f2bf(v.w - bf2f(h.w));
    *reinterpret_cast<ushort4*>(row + k) = h;
    *reinterpret_cast<ushort4*>(row + K + k) = ASIDE ? h : l;
    *reinterpret_cast<ushort4*>(row + 2 * K + k) = ASIDE ? l : h;
}

// ---------------- fixup phase 0: zero the 3 counters ----------------
__global__ __launch_bounds__(64) void zero_counters(int* __restrict__ ctrs)
{
    if (threadIdx.x < 3) ctrs[threadIdx.x * 16] = 0;
}

// ---------------- fixup phase 1: compact borderline indices ----------------
// Membrane decisions happen at mem = c + 0.9*s = 1.0, so flag currents near
// 1.0 (s=0 preimage) or near 0.1 (s=1 preimage).
__global__ __launch_bounds__(256) void scan_bad(const float4* __restrict__ C, int n4,
                                                int* __restrict__ list,
                                                int* __restrict__ counter)
{
    const int i = blockIdx.x * 256 + threadIdx.x;
    const int lane = threadIdx.x & 63;
    int lc = 0;
    int loc[4];
    if (i < n4) {
        float4 v = C[i];
        float vv[4] = {v.x, v.y, v.z, v.w};
#pragma unroll
        for (int c = 0; c < 4; ++c) {
            if ((fabsf(vv[c] - 1.0f) < SDELTA) || (fabsf(vv[c] - 0.1f) < SDELTA))
                loc[lc++] = i * 4 + c;
        }
    }
    int inc = lc;                       // wave inclusive prefix sum
#pragma unroll
    for (int off = 1; off < 64; off <<= 1) {
        int t = __shfl_up(inc, off);
        if (lane >= off) inc += t;
    }
    const int total = __shfl(inc, 63);
    int base = 0;
    if (lane == 63 && total) base = atomicAdd(counter, total);
    base = __shfl(base, 63);
    const int excl = inc - lc;
    for (int j = 0; j < lc; ++j) list[base + excl + j] = loc[j];
}

// ---------------- fixup phase 2: exact f64 dot per bad element ----------------
// Chunked-contiguous wave assignment (locality: consecutive list entries share
// C rows -> shared A row, clustered W rows). MODE 0: A row = P (x).
// MODE 1: A1 recon from C0.  MODE 2: A2 recon from C1.
template <int MODE>
__global__ __launch_bounds__(256) void fixup2_kernel(
    float* __restrict__ C, const float* __restrict__ P,
    const float* __restrict__ Wf, const float* __restrict__ bias,
    const int* __restrict__ list, const int* __restrict__ counter,
    int logN, int K)
{
    const int lane = threadIdx.x & 63;
    const int wave = (blockIdx.x * 256 + threadIdx.x) >> 6;
    const int nw   = gridDim.x * (256 / 64);
    const int nbad = *counter;
    const int chunk = (nbad + nw - 1) / nw;
    const int e0 = wave * chunk;
    const int e1 = min(e0 + chunk, nbad);

    for (int e = e0; e < e1; ++e) {
        const int idx = list[e];
        const int rr = idx >> logN;
        const int cc = idx & ((1 << logN) - 1);
        const float* wrow = Wf + (size_t)cc * K;
        double p = 0.0;
        for (int k = lane * 4; k < K; k += 256) {
            const float4 w4 = ld4(wrow + k);
            float4 a4;
            if (MODE == 0) {
                a4 = ld4(P + (size_t)rr * K + k);
            } else if (MODE == 1) {
                if (rr < 256) a4 = ld4(P + (size_t)rr * K + k);
                else {
                    float4 c0 = ld4(P + (size_t)(rr - 256) * K + k);
                    a4.x = c0.x + ((c0.x > 1.0f) ? 0.9f : 0.0f);
                    a4.y = c0.y + ((c0.y > 1.0f) ? 0.9f : 0.0f);
                    a4.z = c0.z + ((c0.z > 1.0f) ? 0.9f : 0.0f);
                    a4.w = c0.w + ((c0.w > 1.0f) ? 0.9f : 0.0f);
                }
            } else {
                const int i0 = rr & 255, pl = rr >> 8;
                float4 c0 = ld4(P + (size_t)i0 * K + k);
                if (pl == 0) a4 = c0;
                else {
                    float4 ci = ld4(P + (size_t)(i0 + 256) * K + k);
                    float4 m1;
                    m1.x = ci.x + ((c0.x > 1.0f) ? 0.9f : 0.0f);
                    m1.y = ci.y + ((c0.y > 1.0f) ? 0.9f : 0.0f);
                    m1.z = ci.z + ((c0.z > 1.0f) ? 0.9f : 0.0f);
                    m1.w = ci.w + ((c0.w > 1.0f) ? 0.9f : 0.0f);
                    if (pl == 1) a4 = m1;
                    else {
                        a4.x = ci.x + ((m1.x > 1.0f) ? 0.9f : 0.0f);
                        a4.y = ci.y + ((m1.y > 1.0f) ? 0.9f : 0.0f);
                        a4.z = ci.z + ((m1.z > 1.0f) ? 0.9f : 0.0f);
                        a4.w = ci.w + ((m1.w > 1.0f) ? 0.9f : 0.0f);
                    }
                }
            }
            p = fma((double)a4.x, (double)w4.x, p);
            p = fma((double)a4.y, (double)w4.y, p);
            p = fma((double)a4.z, (double)w4.z, p);
            p = fma((double)a4.w, (double)w4.w, p);
        }
#pragma unroll
        for (int off = 32; off; off >>= 1) p += __shfl_down(p, off);
        if (lane == 0) C[idx] = (float)(p + (double)bias[cc]);
    }
}

// ---------------- LIF kernels: emit split A'' ([h|h|l], row width 3*2048) ----------------
__device__ inline void wsplit(ushort_t* row, int k, float4 v)
{
    ushort4 h, l;
    h.x = f2bf(v.x); l.x = f2bf(v.x - bf2f(h.x));
    h.y = f2bf(v.y); l.y = f2bf(v.y - bf2f(h.y));
    h.z = f2bf(v.z); l.z = f2bf(v.z - bf2f(h.z));
    h.w = f2bf(v.w); l.w = f2bf(v.w - bf2f(h.w));
    *reinterpret_cast<ushort4*>(row + k) = h;
    *reinterpret_cast<ushort4*>(row + 2048 + k) = h;
    *reinterpret_cast<ushort4*>(row + 4096 + k) = l;
}

// A1'' rows: 0..255 = mem0(0) = C0; 256..511 = mem0(inf) = C0 + 0.9*[C0>1]
__global__ __launch_bounds__(256) void lif0_split(const float4* __restrict__ C0,
                                                  ushort_t* __restrict__ A1b, int n4)
{
    int i = blockIdx.x * 256 + threadIdx.x;
    if (i >= n4) return;
    const int e0 = i * 4;
    const int r = e0 >> 11, k = e0 & 2047;
    float4 c = C0[i];
    float4 mi;
    mi.x = c.x + ((c.x > 1.0f) ? 0.9f : 0.0f);
    mi.y = c.y + ((c.y > 1.0f) ? 0.9f : 0.0f);
    mi.z = c.z + ((c.z > 1.0f) ? 0.9f : 0.0f);
    mi.w = c.w + ((c.w > 1.0f) ? 0.9f : 0.0f);
    wsplit(A1b + (size_t)r * 6144, k, c);
    wsplit(A1b + (size_t)(256 + r) * 6144, k, mi);
}

// A2'' rows: 0..255 = mem1(0) = C1[0..255]; 256..511 = mem1(1); 512..767 = mem1(inf)
__global__ __launch_bounds__(256) void lif1_split(const float4* __restrict__ C1,
                                                  ushort_t* __restrict__ A2b, int n4)
{
    int i = blockIdx.x * 256 + threadIdx.x;
    if (i >= n4) return;
    const int e0 = i * 4;
    const int r = e0 >> 11, k = e0 & 2047;
    float4 c0 = C1[i], ci = C1[n4 + i];
    float4 m1, m2;
    m1.x = ci.x + ((c0.x > 1.0f) ? 0.9f : 0.0f);
    m1.y = ci.y + ((c0.y > 1.0f) ? 0.9f : 0.0f);
    m1.z = ci.z + ((c0.z > 1.0f) ? 0.9f : 0.0f);
    m1.w = ci.w + ((c0.w > 1.0f) ? 0.9f : 0.0f);
    m2.x = ci.x + ((m1.x > 1.0f) ? 0.9f : 0.0f);
    m2.y = ci.y + ((m1.y > 1.0f) ? 0.9f : 0.0f);
    m2.z = ci.z + ((m1.z > 1.0f) ? 0.9f : 0.0f);
    m2.w = ci.w + ((m1.w > 1.0f) ? 0.9f : 0.0f);
    wsplit(A2b + (size_t)r * 6144, k, c0);
    wsplit(A2b + (size_t)(256 + r) * 6144, k, m1);
    wsplit(A2b + (size_t)(512 + r) * 6144, k, m2);
}

// Final layer + broadcast; grid.y covers 4 time-slices each.
__global__ __launch_bounds__(256) void lif2_bcast(const float4* __restrict__ c2,
                                                  float4* __restrict__ out, int n4)
{
    int i = blockIdx.x * 256 + threadIdx.x;
    if (i >= n4) return;
    float4 c0 = c2[i], c1 = c2[n4 + i], ci = c2[2 * n4 + i];
    float4 m0 = c0, m1, m2, m3;
    m1.x = c1.x + ((m0.x > 1.0f) ? 0.9f : 0.0f);
    m1.y = c1.y + ((m0.y > 1.0f) ? 0.9f : 0.0f);
    m1.z = c1.z + ((m0.z > 1.0f) ? 0.9f : 0.0f);
    m1.w = c1.w + ((m0.w > 1.0f) ? 0.9f : 0.0f);
    m2.x = ci.x + ((m1.x > 1.0f) ? 0.9f : 0.0f);
    m2.y = ci.y + ((m1.y > 1.0f) ? 0.9f : 0.0f);
    m2.z = ci.z + ((m1.z > 1.0f) ? 0.9f : 0.0f);
    m2.w = ci.w + ((m1.w > 1.0f) ? 0.9f : 0.0f);
    m3.x = ci.x + ((m2.x > 1.0f) ? 0.9f : 0.0f);
    m3.y = ci.y + ((m2.y > 1.0f) ? 0.9f : 0.0f);
    m3.z = ci.z + ((m2.z > 1.0f) ? 0.9f : 0.0f);
    m3.w = ci.w + ((m2.w > 1.0f) ? 0.9f : 0.0f);
    int t0 = blockIdx.y * 4;
#pragma unroll
    for (int j = 0; j < 4; ++j) {
        int t = t0 + j;
        float4 v = (t == 0) ? m0 : (t == 1) ? m1 : (t == 2) ? m2 : m3;
        out[(size_t)t * n4 + i] = v;
    }
}

extern "C" void kernel_launch(void* const* d_in, const int* in_sizes, int n_in,
                              void* d_out, int out_size, void* d_ws, size_t ws_size,
                              hipStream_t stream)
{
    const float* x  = (const float*)d_in[0];  // [256,1024]
    const float* W0 = (const float*)d_in[1];  // [2048,1024]
    const float* b0 = (const float*)d_in[2];
    const float* W1 = (const float*)d_in[3];  // [2048,2048]
    const float* b1 = (const float*)d_in[4];
    const float* W2 = (const float*)d_in[5];  // [1024,2048]
    const float* b2 = (const float*)d_in[6];
    float* out = (float*)d_out;
    float* ws  = (float*)d_ws;

    // ws (floats): C0 @0 (512K) | C1 @512K (1M) | C2 @1.5M (768K)  -> 9.4 MB
    float* C0 = ws;
    float* C1 = ws + 524288;
    float* C2 = ws + 1572864;

    // d_out scratch (26.2M floats; ALL overwritten by lif2_bcast at the end):
    ushort_t* Wb0 = (ushort_t*)(out);               // [2048,3072] bf16 = 3,145,728 floats
    ushort_t* Wb1 = (ushort_t*)(out + 3145728);     // [2048,6144] bf16 = 6,291,456 floats
    ushort_t* Wb2 = (ushort_t*)(out + 9437184);     // [1024,6144] bf16 = 3,145,728 floats
    ushort_t* xb  = (ushort_t*)(out + 12582912);    // [256,3072]  bf16 =   393,216 floats
    ushort_t* A1b = (ushort_t*)(out + 12976128);    // [512,6144]  bf16 = 1,572,864 floats
    ushort_t* A2b = (ushort_t*)(out + 14548992);    // [768,6144]  bf16 = 2,359,296 floats
    int* ctrs  = (int*)(out + 16908288);            // 3 counters, 64B apart
    int* list0 = (int*)(out + 16908352);            // cap 512K
    int* list1 = (int*)(out + 17432640);            // cap 1M
    int* list2 = (int*)(out + 18481216);            // cap 768K  (end 19.27M < 26.21M)

    dim3 blk(256);

    zero_counters<<<dim3(1), dim3(64), 0, stream>>>(ctrs);
    cvt_split<1><<<dim3(256),  blk, 0, stream>>>((const float4*)x,  xb,  65536,  10);
    cvt_split<0><<<dim3(2048), blk, 0, stream>>>((const float4*)W0, Wb0, 524288, 10);
    cvt_split<0><<<dim3(4096), blk, 0, stream>>>((const float4*)W1, Wb1, 1048576, 11);
    cvt_split<0><<<dim3(2048), blk, 0, stream>>>((const float4*)W2, Wb2, 524288, 11);

    // GEMM0: cur0 = x @ W0^T + b0  [256,2048], K'=3072
    gemm_bf16<<<dim3(32, 4), blk, 0, stream>>>(xb, Wb0, b0, C0, 2048, 3072);
    scan_bad<<<dim3(512), blk, 0, stream>>>((const float4*)C0, 131072, list0, ctrs + 0);
    fixup2_kernel<0><<<dim3(256), blk, 0, stream>>>(C0, x, W0, b0, list0, ctrs + 0, 11, 1024);
    lif0_split<<<dim3(512), blk, 0, stream>>>((const float4*)C0, A1b, 131072);

    // GEMM1: [cur1(0); cur1(inf)] [512,2048], K'=6144
    gemm_bf16<<<dim3(32, 8), blk, 0, stream>>>(A1b, Wb1, b1, C1, 2048, 6144);
    scan_bad<<<dim3(1024), blk, 0, stream>>>((const float4*)C1, 262144, list1, ctrs + 16);
    fixup2_kernel<1><<<dim3(256), blk, 0, stream>>>(C1, C0, W1, b1, list1, ctrs + 16, 11, 2048);
    lif1_split<<<dim3(512), blk, 0, stream>>>((const float4*)C1, A2b, 131072);

    // GEMM2: 3 layer-2 currents [768,1024], K'=6144
    gemm_bf16<<<dim3(16, 12), blk, 0, stream>>>(A2b, Wb2, b2, C2, 1024, 6144);
    scan_bad<<<dim3(768), blk, 0, stream>>>((const float4*)C2, 196608, list2, ctrs + 32);
    fixup2_kernel<2><<<dim3(256), blk, 0, stream>>>(C2, C1, W2, b2, list2, ctrs + 32, 10, 2048);

    // layer-2 LIF + output broadcast (overwrites all of d_out incl. scratch)
    lif2_bcast<<<dim3(256, 25), blk, 0, stream>>>((const float4*)C2, (float4*)out, 65536);
}

// Round 8
// 227.205 us; speedup vs baseline: 2.7985x; 1.1693x over previous
//
#include <hip/hip_runtime.h>

// SNN with "swapped outputs" bug: stored state = spike (binary), forwarded
// value = membrane. reset = (spk_prev > 1) == 0 always -> mem = cur + 0.9*spk_prev.
// Constant input -> spike patterns fixate: mem0 const t>=1, mem1 t>=2, out t>=3.
// GEMM0 (256x2048,K'=3072); GEMM1 {mem0(0),mem0(inf)} (M=512,K'=6144);
// GEMM2 {mem1(0),mem1(1),mem1(inf)} (M=768,N=1024,K'=6144); broadcast t>=3.
// Split-bf16: A=Ah+Al, W=Wh+Wl; Ah.Wh+Ah.Wl+Al.Wh as ONE GEMM with K'=3K
// (A''=[Ah|Ah|Al], W''=[Wh|Wl|Wh]); error ~1e-5. f64 fixup of elements within
// SDELTA=1e-3 of decision points keeps all spike decisions exact.
//
// Round-7 lesson: 64x64-tile GEMM is AI-bound (32 FLOP/B -> ~800MB staging)
// and latency-exposed -> ~170us. Round 8: m97-structure GEMM — 128x128 tile,
// BK=64, global_load_lds width 16 — with deterministic split-K for occupancy;
// fixed-order reduce fused with bias + borderline scan.

typedef unsigned short ushort_t;
typedef __attribute__((ext_vector_type(8))) short bf16x8;
typedef __attribute__((ext_vector_type(4))) float f32x4;

#define SDELTA 1.0e-3f

__device__ inline ushort_t f2bf(float f) {       // RNE f32 -> bf16
    unsigned u = __float_as_uint(f);
    u += 0x7FFFu + ((u >> 16) & 1u);
    return (ushort_t)(u >> 16);
}
__device__ inline float bf2f(ushort_t h) { return __uint_as_float((unsigned)h << 16); }
__device__ inline float4 ld4(const float* p) { return *reinterpret_cast<const float4*>(p); }

__device__ inline void gload16(const void* g, void* l) {
    __builtin_amdgcn_global_load_lds(
        (__attribute__((address_space(1))) void*)g,
        (__attribute__((address_space(3))) void*)l, 16, 0, 0);
}

// ---- 128x128 split-K GEMM, BK=64, global_load_lds staging (m97 structure) ----
// grid (N/128, M/128, S); partial P[s] = A[:, s*Kc:(s+1)*Kc] @ W^T (no bias)
__global__ __launch_bounds__(256) void gemm_splitk(
    const ushort_t* __restrict__ A,   // [M, K3] bf16
    const ushort_t* __restrict__ W,   // [N, K3] bf16
    float* __restrict__ P,            // [S, M, N] f32 partials
    int M, int N, int K3, int Kc)
{
    __shared__ ushort_t As[128 * 64];
    __shared__ ushort_t Ws[128 * 64];

    const int tid  = threadIdx.x;
    const int lane = tid & 63;
    const int wid  = tid >> 6;
    const int row0 = blockIdx.y * 128;
    const int col0 = blockIdx.x * 128;
    const int k0   = blockIdx.z * Kc;

    // staging: wave wid owns rows [wid*32, wid*32+32), 4 issues x 8 rows each;
    // LDS dest is wave-uniform base + lane*16B (HW rule), layout linear [128][64].
    const int srow = wid * 32 + (lane >> 3);
    const int scol = (lane & 7) * 8;
    const ushort_t* Ag = A + (size_t)(row0 + srow) * K3 + k0 + scol;
    const ushort_t* Wg = W + (size_t)(col0 + srow) * K3 + k0 + scol;

    // compute: wave (wr,wc) owns a 64x64 quadrant; m89 frag layouts
    const int wr = wid >> 1, wc = wid & 1;
    const int l15 = lane & 15;
    const int kh  = lane >> 4;
    const ushort_t* aP = &As[(wr * 64 + l15) * 64 + kh * 8];
    const ushort_t* bP = &Ws[(wc * 64 + l15) * 64 + kh * 8];

    f32x4 acc[4][4] = {};
    const int NIT = Kc / 64;

    for (int it = 0; it < NIT; ++it) {
        const int kk = it * 64;
#pragma unroll
        for (int i = 0; i < 4; ++i) {
            gload16(Ag + (size_t)(i * 8) * K3 + kk, &As[(wid * 32 + i * 8) * 64]);
            gload16(Wg + (size_t)(i * 8) * K3 + kk, &Ws[(wid * 32 + i * 8) * 64]);
        }
        __syncthreads();   // drains vmcnt(0): tile ready
#pragma unroll
        for (int ks = 0; ks < 2; ++ks) {
            bf16x8 af[4], bf[4];
#pragma unroll
            for (int m = 0; m < 4; ++m)
                af[m] = *reinterpret_cast<const bf16x8*>(aP + (m * 16) * 64 + ks * 32);
#pragma unroll
            for (int n = 0; n < 4; ++n)
                bf[n] = *reinterpret_cast<const bf16x8*>(bP + (n * 16) * 64 + ks * 32);
#pragma unroll
            for (int m = 0; m < 4; ++m)
#pragma unroll
                for (int n = 0; n < 4; ++n)
                    acc[m][n] = __builtin_amdgcn_mfma_f32_16x16x32_bf16(
                        af[m], bf[n], acc[m][n], 0, 0, 0);
        }
        __syncthreads();   // all frag reads done before next stage overwrites
    }

    float* Pp = P + ((size_t)blockIdx.z * M + row0) * N + col0;
#pragma unroll
    for (int n = 0; n < 4; ++n) {
        const int col = wc * 64 + n * 16 + l15;
#pragma unroll
        for (int m = 0; m < 4; ++m) {
            const int rb = wr * 64 + m * 16 + kh * 4;
#pragma unroll
            for (int i = 0; i < 4; ++i)
                Pp[(size_t)(rb + i) * N + col] = acc[m][n][i];
        }
    }
}

// ---- fixed-order reduce of S partials + bias, fused with borderline scan ----
template <int S>
__global__ __launch_bounds__(256) void reduce_scan(
    const float4* __restrict__ P,    // [S][n4] float4
    const float* __restrict__ bias,
    float4* __restrict__ C, int n4, int Nmask,
    int* __restrict__ list, int* __restrict__ counter)
{
    const int i = blockIdx.x * 256 + threadIdx.x;
    const int lane = threadIdx.x & 63;
    int lc = 0;
    int loc[4];
    if (i < n4) {
        float4 s = P[i];
#pragma unroll
        for (int j = 1; j < S; ++j) {
            float4 t = P[(size_t)j * n4 + i];
            s.x += t.x; s.y += t.y; s.z += t.z; s.w += t.w;
        }
        const float4 bv = *reinterpret_cast<const float4*>(bias + ((i * 4) & Nmask));
        s.x += bv.x; s.y += bv.y; s.z += bv.z; s.w += bv.w;
        C[i] = s;
        float vv[4] = {s.x, s.y, s.z, s.w};
#pragma unroll
        for (int c = 0; c < 4; ++c)
            if ((fabsf(vv[c] - 1.0f) < SDELTA) || (fabsf(vv[c] - 0.1f) < SDELTA))
                loc[lc++] = i * 4 + c;
    }
    int inc = lc;                       // wave inclusive prefix sum
#pragma unroll
    for (int off = 1; off < 64; off <<= 1) {
        int t = __shfl_up(inc, off);
        if (lane >= off) inc += t;
    }
    const int total = __shfl(inc, 63);
    int base = 0;
    if (lane == 63 && total) base = atomicAdd(counter, total);
    base = __shfl(base, 63);
    const int excl = inc - lc;
    for (int j = 0; j < lc; ++j) list[base + excl + j] = loc[j];
}

// ---------------- split f32 -> [seg0|seg1|seg2] bf16, row width 3K ----------------
// ASIDE=1: [h|h|l] (A operand).  ASIDE=0: [h|l|h] (W operand).
template <int ASIDE>
__global__ __launch_bounds__(256) void cvt_split(const float4* __restrict__ src,
                                                 ushort_t* __restrict__ dst,
                                                 int n4, int logK)
{
    int i = blockIdx.x * 256 + threadIdx.x;
    if (i >= n4) return;
    float4 v = src[i];
    const int K = 1 << logK;
    const int e0 = i * 4;
    const int r = e0 >> logK, k = e0 & (K - 1);
    ushort_t* row = dst + (size_t)r * 3 * K;
    ushort4 h, l;
    h.x = f2bf(v.x); l.x = f2bf(v.x - bf2f(h.x));
    h.y = f2bf(v.y); l.y = f2bf(v.y - bf2f(h.y));
    h.z = f2bf(v.z); l.z = f2bf(v.z - bf2f(h.z));
    h.w = f2bf(v.w); l.w = f2bf(v.w - bf2f(h.w));
    *reinterpret_cast<ushort4*>(row + k) = h;
    *reinterpret_cast<ushort4*>(row + K + k) = ASIDE ? h : l;
    *reinterpret_cast<ushort4*>(row + 2 * K + k) = ASIDE ? l : h;
}

// ---------------- fixup phase 0: zero the 3 counters ----------------
__global__ __launch_bounds__(64) void zero_counters(int* __restrict__ ctrs)
{
    if (threadIdx.x < 3) ctrs[threadIdx.x * 16] = 0;
}

// ---------------- fixup: exact f64 dot per bad element ----------------
// Chunked-contiguous wave assignment (locality). MODE 0: A row = P (x).
// MODE 1: A1 recon from C0.  MODE 2: A2 recon from C1.
template <int MODE>
__global__ __launch_bounds__(256) void fixup2_kernel(
    float* __restrict__ C, const float* __restrict__ P,
    const float* __restrict__ Wf, const float* __restrict__ bias,
    const int* __restrict__ list, const int* __restrict__ counter,
    int logN, int K)
{
    const int lane = threadIdx.x & 63;
    const int wave = (blockIdx.x * 256 + threadIdx.x) >> 6;
    const int nw   = gridDim.x * (256 / 64);
    const int nbad = *counter;
    const int chunk = (nbad + nw - 1) / nw;
    const int e0 = wave * chunk;
    const int e1 = min(e0 + chunk, nbad);

    for (int e = e0; e < e1; ++e) {
        const int idx = list[e];
        const int rr = idx >> logN;
        const int cc = idx & ((1 << logN) - 1);
        const float* wrow = Wf + (size_t)cc * K;
        double p = 0.0;
        for (int k = lane * 4; k < K; k += 256) {
            const float4 w4 = ld4(wrow + k);
            float4 a4;
            if (MODE == 0) {
                a4 = ld4(P + (size_t)rr * K + k);
            } else if (MODE == 1) {
                if (rr < 256) a4 = ld4(P + (size_t)rr * K + k);
                else {
                    float4 c0 = ld4(P + (size_t)(rr - 256) * K + k);
                    a4.x = c0.x + ((c0.x > 1.0f) ? 0.9f : 0.0f);
                    a4.y = c0.y + ((c0.y > 1.0f) ? 0.9f : 0.0f);
                    a4.z = c0.z + ((c0.z > 1.0f) ? 0.9f : 0.0f);
                    a4.w = c0.w + ((c0.w > 1.0f) ? 0.9f : 0.0f);
                }
            } else {
                const int i0 = rr & 255, pl = rr >> 8;
                float4 c0 = ld4(P + (size_t)i0 * K + k);
                if (pl == 0) a4 = c0;
                else {
                    float4 ci = ld4(P + (size_t)(i0 + 256) * K + k);
                    float4 m1;
                    m1.x = ci.x + ((c0.x > 1.0f) ? 0.9f : 0.0f);
                    m1.y = ci.y + ((c0.y > 1.0f) ? 0.9f : 0.0f);
                    m1.z = ci.z + ((c0.z > 1.0f) ? 0.9f : 0.0f);
                    m1.w = ci.w + ((c0.w > 1.0f) ? 0.9f : 0.0f);
                    if (pl == 1) a4 = m1;
                    else {
                        a4.x = ci.x + ((m1.x > 1.0f) ? 0.9f : 0.0f);
                        a4.y = ci.y + ((m1.y > 1.0f) ? 0.9f : 0.0f);
                        a4.z = ci.z + ((m1.z > 1.0f) ? 0.9f : 0.0f);
                        a4.w = ci.w + ((m1.w > 1.0f) ? 0.9f : 0.0f);
                    }
                }
            }
            p = fma((double)a4.x, (double)w4.x, p);
            p = fma((double)a4.y, (double)w4.y, p);
            p = fma((double)a4.z, (double)w4.z, p);
            p = fma((double)a4.w, (double)w4.w, p);
        }
#pragma unroll
        for (int off = 32; off; off >>= 1) p += __shfl_down(p, off);
        if (lane == 0) C[idx] = (float)(p + (double)bias[cc]);
    }
}

// ---------------- LIF kernels: emit split A'' ([h|h|l], row width 3*2048) ----------------
__device__ inline void wsplit(ushort_t* row, int k, float4 v)
{
    ushort4 h, l;
    h.x = f2bf(v.x); l.x = f2bf(v.x - bf2f(h.x));
    h.y = f2bf(v.y); l.y = f2bf(v.y - bf2f(h.y));
    h.z = f2bf(v.z); l.z = f2bf(v.z - bf2f(h.z));
    h.w = f2bf(v.w); l.w = f2bf(v.w - bf2f(h.w));
    *reinterpret_cast<ushort4*>(row + k) = h;
    *reinterpret_cast<ushort4*>(row + 2048 + k) = h;
    *reinterpret_cast<ushort4*>(row + 4096 + k) = l;
}

// A1'' rows: 0..255 = mem0(0) = C0; 256..511 = mem0(inf) = C0 + 0.9*[C0>1]
__global__ __launch_bounds__(256) void lif0_split(const float4* __restrict__ C0,
                                                  ushort_t* __restrict__ A1b, int n4)
{
    int i = blockIdx.x * 256 + threadIdx.x;
    if (i >= n4) return;
    const int e0 = i * 4;
    const int r = e0 >> 11, k = e0 & 2047;
    float4 c = C0[i];
    float4 mi;
    mi.x = c.x + ((c.x > 1.0f) ? 0.9f : 0.0f);
    mi.y = c.y + ((c.y > 1.0f) ? 0.9f : 0.0f);
    mi.z = c.z + ((c.z > 1.0f) ? 0.9f : 0.0f);
    mi.w = c.w + ((c.w > 1.0f) ? 0.9f : 0.0f);
    wsplit(A1b + (size_t)r * 6144, k, c);
    wsplit(A1b + (size_t)(256 + r) * 6144, k, mi);
}

// A2'' rows: 0..255 = mem1(0) = C1[0..255]; 256..511 = mem1(1); 512..767 = mem1(inf)
__global__ __launch_bounds__(256) void lif1_split(const float4* __restrict__ C1,
                                                  ushort_t* __restrict__ A2b, int n4)
{
    int i = blockIdx.x * 256 + threadIdx.x;
    if (i >= n4) return;
    const int e0 = i * 4;
    const int r = e0 >> 11, k = e0 & 2047;
    float4 c0 = C1[i], ci = C1[n4 + i];
    float4 m1, m2;
    m1.x = ci.x + ((c0.x > 1.0f) ? 0.9f : 0.0f);
    m1.y = ci.y + ((c0.y > 1.0f) ? 0.9f : 0.0f);
    m1.z = ci.z + ((c0.z > 1.0f) ? 0.9f : 0.0f);
    m1.w = ci.w + ((c0.w > 1.0f) ? 0.9f : 0.0f);
    m2.x = ci.x + ((m1.x > 1.0f) ? 0.9f : 0.0f);
    m2.y = ci.y + ((m1.y > 1.0f) ? 0.9f : 0.0f);
    m2.z = ci.z + ((m1.z > 1.0f) ? 0.9f : 0.0f);
    m2.w = ci.w + ((m1.w > 1.0f) ? 0.9f : 0.0f);
    wsplit(A2b + (size_t)r * 6144, k, c0);
    wsplit(A2b + (size_t)(256 + r) * 6144, k, m1);
    wsplit(A2b + (size_t)(512 + r) * 6144, k, m2);
}

// Final layer + broadcast; grid.y covers 4 time-slices each.
__global__ __launch_bounds__(256) void lif2_bcast(const float4* __restrict__ c2,
                                                  float4* __restrict__ out, int n4)
{
    int i = blockIdx.x * 256 + threadIdx.x;
    if (i >= n4) return;
    float4 c0 = c2[i], c1 = c2[n4 + i], ci = c2[2 * n4 + i];
    float4 m0 = c0, m1, m2, m3;
    m1.x = c1.x + ((m0.x > 1.0f) ? 0.9f : 0.0f);
    m1.y = c1.y + ((m0.y > 1.0f) ? 0.9f : 0.0f);
    m1.z = c1.z + ((m0.z > 1.0f) ? 0.9f : 0.0f);
    m1.w = c1.w + ((m0.w > 1.0f) ? 0.9f : 0.0f);
    m2.x = ci.x + ((m1.x > 1.0f) ? 0.9f : 0.0f);
    m2.y = ci.y + ((m1.y > 1.0f) ? 0.9f : 0.0f);
    m2.z = ci.z + ((m1.z > 1.0f) ? 0.9f : 0.0f);
    m2.w = ci.w + ((m1.w > 1.0f) ? 0.9f : 0.0f);
    m3.x = ci.x + ((m2.x > 1.0f) ? 0.9f : 0.0f);
    m3.y = ci.y + ((m2.y > 1.0f) ? 0.9f : 0.0f);
    m3.z = ci.z + ((m2.z > 1.0f) ? 0.9f : 0.0f);
    m3.w = ci.w + ((m2.w > 1.0f) ? 0.9f : 0.0f);
    int t0 = blockIdx.y * 4;
#pragma unroll
    for (int j = 0; j < 4; ++j) {
        int t = t0 + j;
        float4 v = (t == 0) ? m0 : (t == 1) ? m1 : (t == 2) ? m2 : m3;
        out[(size_t)t * n4 + i] = v;
    }
}

extern "C" void kernel_launch(void* const* d_in, const int* in_sizes, int n_in,
                              void* d_out, int out_size, void* d_ws, size_t ws_size,
                              hipStream_t stream)
{
    const float* x  = (const float*)d_in[0];  // [256,1024]
    const float* W0 = (const float*)d_in[1];  // [2048,1024]
    const float* b0 = (const float*)d_in[2];
    const float* W1 = (const float*)d_in[3];  // [2048,2048]
    const float* b1 = (const float*)d_in[4];
    const float* W2 = (const float*)d_in[5];  // [1024,2048]
    const float* b2 = (const float*)d_in[6];
    float* out = (float*)d_out;
    float* ws  = (float*)d_ws;

    // ws (floats): C0 @0 (512K) | C1 @512K (1M) | C2 @1.5M (768K)  -> 9.4 MB
    float* C0 = ws;
    float* C1 = ws + 524288;
    float* C2 = ws + 1572864;

    // d_out scratch (26.2M floats; ALL overwritten by lif2_bcast at the end):
    ushort_t* Wb0 = (ushort_t*)(out);               // [2048,3072] bf16
    ushort_t* Wb1 = (ushort_t*)(out + 3145728);     // [2048,6144] bf16
    ushort_t* Wb2 = (ushort_t*)(out + 9437184);     // [1024,6144] bf16
    ushort_t* xb  = (ushort_t*)(out + 12582912);    // [256,3072]  bf16
    ushort_t* A1b = (ushort_t*)(out + 12976128);    // [512,6144]  bf16
    ushort_t* A2b = (ushort_t*)(out + 14548992);    // [768,6144]  bf16
    int* ctrs  = (int*)(out + 16908288);            // 3 counters, 64B apart
    int* list0 = (int*)(out + 16908352);
    int* list1 = (int*)(out + 17432640);
    int* list2 = (int*)(out + 18481216);
    float* Pbuf = out + 19267648;                   // split-K partials, 4M floats cap

    dim3 blk(256);

    zero_counters<<<dim3(1), dim3(64), 0, stream>>>(ctrs);
    cvt_split<1><<<dim3(256),  blk, 0, stream>>>((const float4*)x,  xb,  65536,  10);
    cvt_split<0><<<dim3(2048), blk, 0, stream>>>((const float4*)W0, Wb0, 524288, 10);
    cvt_split<0><<<dim3(4096), blk, 0, stream>>>((const float4*)W1, Wb1, 1048576, 11);
    cvt_split<0><<<dim3(2048), blk, 0, stream>>>((const float4*)W2, Wb2, 524288, 11);

    // GEMM0: [256,2048], K'=3072, split-K x8 (Kc=384) -> 16x2x8 = 256 blocks
    gemm_splitk<<<dim3(16, 2, 8), blk, 0, stream>>>(xb, Wb0, Pbuf, 256, 2048, 3072, 384);
    reduce_scan<8><<<dim3(512), blk, 0, stream>>>((const float4*)Pbuf, b0, (float4*)C0,
                                                  131072, 2047, list0, ctrs + 0);
    fixup2_kernel<0><<<dim3(256), blk, 0, stream>>>(C0, x, W0, b0, list0, ctrs + 0, 11, 1024);
    lif0_split<<<dim3(512), blk, 0, stream>>>((const float4*)C0, A1b, 131072);

    // GEMM1: [512,2048], K'=6144, split-K x4 (Kc=1536) -> 16x4x4 = 256 blocks
    gemm_splitk<<<dim3(16, 4, 4), blk, 0, stream>>>(A1b, Wb1, Pbuf, 512, 2048, 6144, 1536);
    reduce_scan<4><<<dim3(1024), blk, 0, stream>>>((const float4*)Pbuf, b1, (float4*)C1,
                                                   262144, 2047, list1, ctrs + 16);
    fixup2_kernel<1><<<dim3(256), blk, 0, stream>>>(C1, C0, W1, b1, list1, ctrs + 16, 11, 2048);
    lif1_split<<<dim3(512), blk, 0, stream>>>((const float4*)C1, A2b, 131072);

    // GEMM2: [768,1024], K'=6144, split-K x4 (Kc=1536) -> 8x6x4 = 192 blocks
    gemm_splitk<<<dim3(8, 6, 4), blk, 0, stream>>>(A2b, Wb2, Pbuf, 768, 1024, 6144, 1536);
    reduce_scan<4><<<dim3(768), blk, 0, stream>>>((const float4*)Pbuf, b2, (float4*)C2,
                                                  196608, 1023, list2, ctrs + 32);
    fixup2_kernel<2><<<dim3(256), blk, 0, stream>>>(C2, C1, W2, b2, list2, ctrs + 32, 10, 2048);

    // layer-2 LIF + output broadcast (overwrites all of d_out incl. scratch)
    lif2_bcast<<<dim3(256, 25), blk, 0, stream>>>((const float4*)C2, (float4*)out, 65536);
}

// Round 9
// 201.388 us; speedup vs baseline: 3.1573x; 1.1282x over previous
//
#include <hip/hip_runtime.h>

// SNN with "swapped outputs" bug: stored state = spike (binary), forwarded
// value = membrane. reset = (spk_prev > 1) == 0 always -> mem = cur + 0.9*spk_prev.
// Constant input -> spike patterns fixate: mem0 const t>=1, mem1 t>=2, out t>=3.
// GEMM0 (256x2048,K'=3072); GEMM1 {mem0(0),mem0(inf)} (M=512,K'=6144);
// GEMM2 {mem1(0),mem1(1),mem1(inf)} (M=768,N=1024,K'=6144); broadcast t>=3.
// Split-bf16: A=Ah+Al, W=Wh+Wl; Ah.Wh+Ah.Wl+Al.Wh as ONE GEMM with K'=3K.
// f64 fixup of elements within SDELTA=1e-3 of decision points (exact decisions).
//
// Round-9: 14 -> 11 kernels. cvts merged; lif-split fused into reduce_scan
// (fixup patches C AND the A'' bf16 entries); GEMM1 split-K x8 (2 blocks/CU).

typedef unsigned short ushort_t;
typedef __attribute__((ext_vector_type(8))) short bf16x8;
typedef __attribute__((ext_vector_type(4))) float f32x4;

#define SDELTA 1.0e-3f
#define LCAP 65536

__device__ inline ushort_t f2bf(float f) {       // RNE f32 -> bf16
    unsigned u = __float_as_uint(f);
    u += 0x7FFFu + ((u >> 16) & 1u);
    return (ushort_t)(u >> 16);
}
__device__ inline float bf2f(ushort_t h) { return __uint_as_float((unsigned)h << 16); }
__device__ inline float4 ld4(const float* p) { return *reinterpret_cast<const float4*>(p); }

__device__ inline void gload16(const void* g, void* l) {
    __builtin_amdgcn_global_load_lds(
        (__attribute__((address_space(1))) void*)g,
        (__attribute__((address_space(3))) void*)l, 16, 0, 0);
}

// ---- 128x128 split-K GEMM, BK=64, global_load_lds staging (m97 structure) ----
__global__ __launch_bounds__(256) void gemm_splitk(
    const ushort_t* __restrict__ A,   // [M, K3] bf16
    const ushort_t* __restrict__ W,   // [N, K3] bf16
    float* __restrict__ P,            // [S, M, N] f32 partials
    int M, int N, int K3, int Kc)
{
    __shared__ ushort_t As[128 * 64];
    __shared__ ushort_t Ws[128 * 64];

    const int tid  = threadIdx.x;
    const int lane = tid & 63;
    const int wid  = tid >> 6;
    const int row0 = blockIdx.y * 128;
    const int col0 = blockIdx.x * 128;
    const int k0   = blockIdx.z * Kc;

    const int srow = wid * 32 + (lane >> 3);
    const int scol = (lane & 7) * 8;
    const ushort_t* Ag = A + (size_t)(row0 + srow) * K3 + k0 + scol;
    const ushort_t* Wg = W + (size_t)(col0 + srow) * K3 + k0 + scol;

    const int wr = wid >> 1, wc = wid & 1;
    const int l15 = lane & 15;
    const int kh  = lane >> 4;
    const ushort_t* aP = &As[(wr * 64 + l15) * 64 + kh * 8];
    const ushort_t* bP = &Ws[(wc * 64 + l15) * 64 + kh * 8];

    f32x4 acc[4][4] = {};
    const int NIT = Kc / 64;

    for (int it = 0; it < NIT; ++it) {
        const int kk = it * 64;
#pragma unroll
        for (int i = 0; i < 4; ++i) {
            gload16(Ag + (size_t)(i * 8) * K3 + kk, &As[(wid * 32 + i * 8) * 64]);
            gload16(Wg + (size_t)(i * 8) * K3 + kk, &Ws[(wid * 32 + i * 8) * 64]);
        }
        __syncthreads();
#pragma unroll
        for (int ks = 0; ks < 2; ++ks) {
            bf16x8 af[4], bf[4];
#pragma unroll
            for (int m = 0; m < 4; ++m)
                af[m] = *reinterpret_cast<const bf16x8*>(aP + (m * 16) * 64 + ks * 32);
#pragma unroll
            for (int n = 0; n < 4; ++n)
                bf[n] = *reinterpret_cast<const bf16x8*>(bP + (n * 16) * 64 + ks * 32);
#pragma unroll
            for (int m = 0; m < 4; ++m)
#pragma unroll
                for (int n = 0; n < 4; ++n)
                    acc[m][n] = __builtin_amdgcn_mfma_f32_16x16x32_bf16(
                        af[m], bf[n], acc[m][n], 0, 0, 0);
        }
        __syncthreads();
    }

    float* Pp = P + ((size_t)blockIdx.z * M + row0) * N + col0;
#pragma unroll
    for (int n = 0; n < 4; ++n) {
        const int col = wc * 64 + n * 16 + l15;
#pragma unroll
        for (int m = 0; m < 4; ++m) {
            const int rb = wr * 64 + m * 16 + kh * 4;
#pragma unroll
            for (int i = 0; i < 4; ++i)
                Pp[(size_t)(rb + i) * N + col] = acc[m][n][i];
        }
    }
}

// ---------------- merged split-conversions + counter zeroing ----------------
__device__ inline void do_split(const float4* src, ushort_t* dst, int i,
                                int logK, bool aside)
{
    float4 v = src[i];
    const int K = 1 << logK;
    const int e0 = i * 4;
    const int r = e0 >> logK, k = e0 & (K - 1);
    ushort_t* row = dst + (size_t)r * 3 * K;
    ushort4 h, l;
    h.x = f2bf(v.x); l.x = f2bf(v.x - bf2f(h.x));
    h.y = f2bf(v.y); l.y = f2bf(v.y - bf2f(h.y));
    h.z = f2bf(v.z); l.z = f2bf(v.z - bf2f(h.z));
    h.w = f2bf(v.w); l.w = f2bf(v.w - bf2f(h.w));
    *reinterpret_cast<ushort4*>(row + k) = h;
    *reinterpret_cast<ushort4*>(row + K + k) = aside ? h : l;
    *reinterpret_cast<ushort4*>(row + 2 * K + k) = aside ? l : h;
}

__global__ __launch_bounds__(256) void cvt_all(
    const float4* __restrict__ x,  const float4* __restrict__ W0,
    const float4* __restrict__ W1, const float4* __restrict__ W2,
    ushort_t* __restrict__ xb,  ushort_t* __restrict__ Wb0,
    ushort_t* __restrict__ Wb1, ushort_t* __restrict__ Wb2,
    int* __restrict__ ctrs)
{
    const int b = blockIdx.x, tid = threadIdx.x;
    if (b == 0 && tid < 3) ctrs[tid * 16] = 0;
    if (b < 256)        do_split(x,  xb,  b * 256 + tid,          10, true);
    else if (b < 2304)  do_split(W0, Wb0, (b - 256) * 256 + tid,  10, false);
    else if (b < 6400)  do_split(W1, Wb1, (b - 2304) * 256 + tid, 11, false);
    else                do_split(W2, Wb2, (b - 6400) * 256 + tid, 11, false);
}

// ---------------- wave compaction of flagged indices ----------------
__device__ inline void emit(const int* loc, int lc, int* list, int* counter)
{
    const int lane = threadIdx.x & 63;
    int inc = lc;
#pragma unroll
    for (int off = 1; off < 64; off <<= 1) {
        int t = __shfl_up(inc, off);
        if (lane >= off) inc += t;
    }
    const int total = __shfl(inc, 63);
    int base = 0;
    if (lane == 63 && total) base = atomicAdd(counter, total);
    base = __shfl(base, 63);
    const int excl = inc - lc;
    for (int j = 0; j < lc; ++j) {
        int p = base + excl + j;
        if (p < LCAP) list[p] = loc[j];
    }
}

__device__ inline int flag4(float4 v, int e0, int* loc, int lc)
{
    float vv[4] = {v.x, v.y, v.z, v.w};
#pragma unroll
    for (int c = 0; c < 4; ++c)
        if ((fabsf(vv[c] - 1.0f) < SDELTA) || (fabsf(vv[c] - 0.1f) < SDELTA))
            loc[lc++] = e0 + c;
    return lc;
}

__device__ inline void wsplit(ushort_t* row, int k, float4 v)
{
    ushort4 h, l;
    h.x = f2bf(v.x); l.x = f2bf(v.x - bf2f(h.x));
    h.y = f2bf(v.y); l.y = f2bf(v.y - bf2f(h.y));
    h.z = f2bf(v.z); l.z = f2bf(v.z - bf2f(h.z));
    h.w = f2bf(v.w); l.w = f2bf(v.w - bf2f(h.w));
    *reinterpret_cast<ushort4*>(row + k) = h;
    *reinterpret_cast<ushort4*>(row + 2048 + k) = h;
    *reinterpret_cast<ushort4*>(row + 4096 + k) = l;
}

__device__ inline float4 lifstep(float4 cur, float4 gate)
{
    float4 o;
    o.x = cur.x + ((gate.x > 1.0f) ? 0.9f : 0.0f);
    o.y = cur.y + ((gate.y > 1.0f) ? 0.9f : 0.0f);
    o.z = cur.z + ((gate.z > 1.0f) ? 0.9f : 0.0f);
    o.w = cur.w + ((gate.w > 1.0f) ? 0.9f : 0.0f);
    return o;
}

// ---- layer 0 epilogue: reduce S=8 + bias, scan, C0 write, A1'' split ----
__global__ __launch_bounds__(256) void fused0(
    const float4* __restrict__ P, const float* __restrict__ bias,
    float4* __restrict__ C0, ushort_t* __restrict__ A1b,
    int* __restrict__ list, int* __restrict__ counter)
{
    const int i = blockIdx.x * 256 + threadIdx.x;   // < 131072
    float4 s = P[i];
#pragma unroll
    for (int j = 1; j < 8; ++j) {
        float4 t = P[(size_t)j * 131072 + i];
        s.x += t.x; s.y += t.y; s.z += t.z; s.w += t.w;
    }
    const float4 bv = *reinterpret_cast<const float4*>(bias + ((i * 4) & 2047));
    s.x += bv.x; s.y += bv.y; s.z += bv.z; s.w += bv.w;
    C0[i] = s;
    int loc[4];
    int lc = flag4(s, i * 4, loc, 0);
    emit(loc, lc, list, counter);
    float4 mi = lifstep(s, s);
    const int e0 = i * 4, r = e0 >> 11, k = e0 & 2047;
    wsplit(A1b + (size_t)r * 6144, k, s);
    wsplit(A1b + (size_t)(256 + r) * 6144, k, mi);
}

// ---- layer 1 epilogue: reduce S=8 both halves, scan, C1, A2'' split ----
__global__ __launch_bounds__(256) void fused1(
    const float4* __restrict__ P, const float* __restrict__ bias,
    float4* __restrict__ C1, ushort_t* __restrict__ A2b,
    int* __restrict__ list, int* __restrict__ counter)
{
    const int i = blockIdx.x * 256 + threadIdx.x;   // < 131072
    float4 c0 = P[i];
    float4 ci = P[131072 + i];
#pragma unroll
    for (int j = 1; j < 8; ++j) {
        float4 t0 = P[(size_t)j * 262144 + i];
        float4 t1 = P[(size_t)j * 262144 + 131072 + i];
        c0.x += t0.x; c0.y += t0.y; c0.z += t0.z; c0.w += t0.w;
        ci.x += t1.x; ci.y += t1.y; ci.z += t1.z; ci.w += t1.w;
    }
    const float4 bv = *reinterpret_cast<const float4*>(bias + ((i * 4) & 2047));
    c0.x += bv.x; c0.y += bv.y; c0.z += bv.z; c0.w += bv.w;
    ci.x += bv.x; ci.y += bv.y; ci.z += bv.z; ci.w += bv.w;
    C1[i] = c0;
    C1[131072 + i] = ci;
    int loc[8];
    int lc = flag4(c0, i * 4, loc, 0);
    lc = flag4(ci, (131072 + i) * 4, loc, lc);
    emit(loc, lc, list, counter);
    float4 m1 = lifstep(ci, c0);
    float4 m2 = lifstep(ci, m1);
    const int e0 = i * 4, r = e0 >> 11, k = e0 & 2047;
    wsplit(A2b + (size_t)r * 6144, k, c0);
    wsplit(A2b + (size_t)(256 + r) * 6144, k, m1);
    wsplit(A2b + (size_t)(512 + r) * 6144, k, m2);
}

// ---- layer 2 epilogue: reduce S=4 + bias + scan -> C2 ----
__global__ __launch_bounds__(256) void reduce_scan2(
    const float4* __restrict__ P, const float* __restrict__ bias,
    float4* __restrict__ C2, int* __restrict__ list, int* __restrict__ counter)
{
    const int i = blockIdx.x * 256 + threadIdx.x;   // < 196608
    float4 s = P[i];
#pragma unroll
    for (int j = 1; j < 4; ++j) {
        float4 t = P[(size_t)j * 196608 + i];
        s.x += t.x; s.y += t.y; s.z += t.z; s.w += t.w;
    }
    const float4 bv = *reinterpret_cast<const float4*>(bias + ((i * 4) & 1023));
    s.x += bv.x; s.y += bv.y; s.z += bv.z; s.w += bv.w;
    C2[i] = s;
    int loc[4];
    int lc = flag4(s, i * 4, loc, 0);
    emit(loc, lc, list, counter);
}

// ---------------- fixups: exact f64 dots, patch C and A'' ----------------
__device__ inline void patch3(ushort_t* row, int c, float v)
{
    ushort_t h = f2bf(v);
    ushort_t l = f2bf(v - bf2f(h));
    row[c] = h; row[2048 + c] = h; row[4096 + c] = l;
}
__device__ inline double wred(double p)
{
#pragma unroll
    for (int off = 32; off; off >>= 1) p += __shfl_down(p, off);
    return __shfl(p, 0);
}

__global__ __launch_bounds__(256) void fixup0(
    float* __restrict__ C0, ushort_t* __restrict__ A1b,
    const float* __restrict__ X, const float* __restrict__ W0,
    const float* __restrict__ b0,
    const int* __restrict__ list, const int* __restrict__ counter)
{
    const int lane = threadIdx.x & 63;
    const int wave = (blockIdx.x * 256 + threadIdx.x) >> 6;
    const int nw = gridDim.x * 4;
    const int nbad = min(*counter, LCAP);
    const int chunk = (nbad + nw - 1) / nw;
    for (int e = wave * chunk; e < min(wave * chunk + chunk, nbad); ++e) {
        const int idx = list[e];
        const int rr = idx >> 11, cc = idx & 2047;
        double p = 0.0;
        for (int k = lane * 4; k < 1024; k += 256) {
            float4 a4 = ld4(X + (size_t)rr * 1024 + k);
            float4 w4 = ld4(W0 + (size_t)cc * 1024 + k);
            p = fma((double)a4.x, (double)w4.x, p);
            p = fma((double)a4.y, (double)w4.y, p);
            p = fma((double)a4.z, (double)w4.z, p);
            p = fma((double)a4.w, (double)w4.w, p);
        }
        const double tot = wred(p);
        if (lane == 0) {
            float c = (float)(tot + (double)b0[cc]);
            C0[idx] = c;
            float mi = c + ((c > 1.0f) ? 0.9f : 0.0f);
            patch3(A1b + (size_t)rr * 6144, cc, c);
            patch3(A1b + (size_t)(256 + rr) * 6144, cc, mi);
        }
    }
}

__global__ __launch_bounds__(256) void fixup1(
    float* __restrict__ C1, ushort_t* __restrict__ A2b,
    const float* __restrict__ C0, const float* __restrict__ W1,
    const float* __restrict__ b1,
    const int* __restrict__ list, const int* __restrict__ counter)
{
    const int lane = threadIdx.x & 63;
    const int wave = (blockIdx.x * 256 + threadIdx.x) >> 6;
    const int nw = gridDim.x * 4;
    const int nbad = min(*counter, LCAP);
    const int chunk = (nbad + nw - 1) / nw;
    for (int e = wave * chunk; e < min(wave * chunk + chunk, nbad); ++e) {
        const int idx = list[e];
        const int rr = idx >> 11, cc = idx & 2047;
        const int rp = rr & 255;
        double p0 = 0.0, p1 = 0.0;
        for (int k = lane * 4; k < 2048; k += 256) {
            float4 a4 = ld4(C0 + (size_t)rp * 2048 + k);   // mem0(0) row
            float4 w4 = ld4(W1 + (size_t)cc * 2048 + k);
            float4 b4 = lifstep(a4, a4);                    // mem0(inf) row
            p0 = fma((double)a4.x, (double)w4.x, p0);
            p0 = fma((double)a4.y, (double)w4.y, p0);
            p0 = fma((double)a4.z, (double)w4.z, p0);
            p0 = fma((double)a4.w, (double)w4.w, p0);
            p1 = fma((double)b4.x, (double)w4.x, p1);
            p1 = fma((double)b4.y, (double)w4.y, p1);
            p1 = fma((double)b4.z, (double)w4.z, p1);
            p1 = fma((double)b4.w, (double)w4.w, p1);
        }
        const double t0 = wred(p0);
        const double t1 = wred(p1);
        if (lane == 0) {
            float c0 = (float)(t0 + (double)b1[cc]);
            float ci = (float)(t1 + (double)b1[cc]);
            C1[(size_t)rp * 2048 + cc] = c0;
            C1[(size_t)(256 + rp) * 2048 + cc] = ci;
            float m1 = ci + ((c0 > 1.0f) ? 0.9f : 0.0f);
            float m2 = ci + ((m1 > 1.0f) ? 0.9f : 0.0f);
            patch3(A2b + (size_t)rp * 6144, cc, c0);
            patch3(A2b + (size_t)(256 + rp) * 6144, cc, m1);
            patch3(A2b + (size_t)(512 + rp) * 6144, cc, m2);
        }
    }
}

__global__ __launch_bounds__(256) void fixup2(
    float* __restrict__ C2, const float* __restrict__ C1,
    const float* __restrict__ W2, const float* __restrict__ b2,
    const int* __restrict__ list, const int* __restrict__ counter)
{
    const int lane = threadIdx.x & 63;
    const int wave = (blockIdx.x * 256 + threadIdx.x) >> 6;
    const int nw = gridDim.x * 4;
    const int nbad = min(*counter, LCAP);
    const int chunk = (nbad + nw - 1) / nw;
    for (int e = wave * chunk; e < min(wave * chunk + chunk, nbad); ++e) {
        const int idx = list[e];
        const int rr = idx >> 10, cc = idx & 1023;
        const int rp = rr & 255;
        double pA = 0.0, pB = 0.0, pC = 0.0;
        for (int k = lane * 4; k < 2048; k += 256) {
            float4 c04 = ld4(C1 + (size_t)rp * 2048 + k);
            float4 ci4 = ld4(C1 + (size_t)(256 + rp) * 2048 + k);
            float4 w4  = ld4(W2 + (size_t)cc * 2048 + k);
            float4 m14 = lifstep(ci4, c04);
            float4 m24 = lifstep(ci4, m14);
            pA = fma((double)c04.x, (double)w4.x, pA);
            pA = fma((double)c04.y, (double)w4.y, pA);
            pA = fma((double)c04.z, (double)w4.z, pA);
            pA = fma((double)c04.w, (double)w4.w, pA);
            pB = fma((double)m14.x, (double)w4.x, pB);
            pB = fma((double)m14.y, (double)w4.y, pB);
            pB = fma((double)m14.z, (double)w4.z, pB);
            pB = fma((double)m14.w, (double)w4.w, pB);
            pC = fma((double)m24.x, (double)w4.x, pC);
            pC = fma((double)m24.y, (double)w4.y, pC);
            pC = fma((double)m24.z, (double)w4.z, pC);
            pC = fma((double)m24.w, (double)w4.w, pC);
        }
        const double tA = wred(pA);
        const double tB = wred(pB);
        const double tC = wred(pC);
        if (lane == 0) {
            C2[(size_t)rp * 1024 + cc]         = (float)(tA + (double)b2[cc]);
            C2[(size_t)(256 + rp) * 1024 + cc] = (float)(tB + (double)b2[cc]);
            C2[(size_t)(512 + rp) * 1024 + cc] = (float)(tC + (double)b2[cc]);
        }
    }
}

// Final layer + broadcast; grid.y covers 4 time-slices each.
__global__ __launch_bounds__(256) void lif2_bcast(const float4* __restrict__ c2,
                                                  float4* __restrict__ out, int n4)
{
    int i = blockIdx.x * 256 + threadIdx.x;
    if (i >= n4) return;
    float4 c0 = c2[i], c1 = c2[n4 + i], ci = c2[2 * n4 + i];
    float4 m0 = c0;
    float4 m1 = lifstep(c1, m0);
    float4 m2 = lifstep(ci, m1);
    float4 m3 = lifstep(ci, m2);
    int t0 = blockIdx.y * 4;
#pragma unroll
    for (int j = 0; j < 4; ++j) {
        int t = t0 + j;
        float4 v = (t == 0) ? m0 : (t == 1) ? m1 : (t == 2) ? m2 : m3;
        out[(size_t)t * n4 + i] = v;
    }
}

extern "C" void kernel_launch(void* const* d_in, const int* in_sizes, int n_in,
                              void* d_out, int out_size, void* d_ws, size_t ws_size,
                              hipStream_t stream)
{
    const float* x  = (const float*)d_in[0];  // [256,1024]
    const float* W0 = (const float*)d_in[1];  // [2048,1024]
    const float* b0 = (const float*)d_in[2];
    const float* W1 = (const float*)d_in[3];  // [2048,2048]
    const float* b1 = (const float*)d_in[4];
    const float* W2 = (const float*)d_in[5];  // [1024,2048]
    const float* b2 = (const float*)d_in[6];
    float* out = (float*)d_out;
    float* ws  = (float*)d_ws;

    // ws (floats): C0 0.5M | C1 1M | C2 0.75M | ctrs 64 | lists 3x64K  = 10.2MB
    float* C0 = ws;
    float* C1 = ws + 524288;
    float* C2 = ws + 1572864;
    int* ctrs  = (int*)(ws + 2359296);
    int* list0 = (int*)(ws + 2359360);
    int* list1 = (int*)(ws + 2424896);
    int* list2 = (int*)(ws + 2490432);

    // d_out scratch (ALL overwritten by lif2_bcast at the end):
    ushort_t* Wb0 = (ushort_t*)(out);               // [2048,3072] bf16
    ushort_t* Wb1 = (ushort_t*)(out + 3145728);     // [2048,6144] bf16
    ushort_t* Wb2 = (ushort_t*)(out + 9437184);     // [1024,6144] bf16
    ushort_t* xb  = (ushort_t*)(out + 12582912);    // [256,3072]  bf16
    ushort_t* A1b = (ushort_t*)(out + 12976128);    // [512,6144]  bf16
    ushort_t* A2b = (ushort_t*)(out + 14548992);    // [768,6144]  bf16
    float* Pbuf   = out + 16908288;                 // split-K partials, 8.4M floats

    dim3 blk(256);

    // 1: all split-conversions + counter zeroing
    cvt_all<<<dim3(8448), blk, 0, stream>>>((const float4*)x, (const float4*)W0,
                                            (const float4*)W1, (const float4*)W2,
                                            xb, Wb0, Wb1, Wb2, ctrs);

    // 2-4: layer 0. GEMM [256,2048] K'=3072, S=8 (Kc=384) -> 256 blocks
    gemm_splitk<<<dim3(16, 2, 8), blk, 0, stream>>>(xb, Wb0, Pbuf, 256, 2048, 3072, 384);
    fused0<<<dim3(512), blk, 0, stream>>>((const float4*)Pbuf, b0, (float4*)C0,
                                          A1b, list0, ctrs + 0);
    fixup0<<<dim3(256), blk, 0, stream>>>(C0, A1b, x, W0, b0, list0, ctrs + 0);

    // 5-7: layer 1. GEMM [512,2048] K'=6144, S=8 (Kc=768) -> 512 blocks (2/CU)
    gemm_splitk<<<dim3(16, 4, 8), blk, 0, stream>>>(A1b, Wb1, Pbuf, 512, 2048, 6144, 768);
    fused1<<<dim3(512), blk, 0, stream>>>((const float4*)Pbuf, b1, (float4*)C1,
                                          A2b, list1, ctrs + 16);
    fixup1<<<dim3(256), blk, 0, stream>>>(C1, A2b, C0, W1, b1, list1, ctrs + 16);

    // 8-10: layer 2. GEMM [768,1024] K'=6144, S=4 (Kc=1536) -> 192 blocks
    gemm_splitk<<<dim3(8, 6, 4), blk, 0, stream>>>(A2b, Wb2, Pbuf, 768, 1024, 6144, 1536);
    reduce_scan2<<<dim3(768), blk, 0, stream>>>((const float4*)Pbuf, b2, (float4*)C2,
                                                list2, ctrs + 32);
    fixup2<<<dim3(256), blk, 0, stream>>>(C2, C1, W2, b2, list2, ctrs + 32);

    // 11: layer-2 LIF chain + output broadcast (overwrites all of d_out)
    lif2_bcast<<<dim3(256, 25), blk, 0, stream>>>((const float4*)C2, (float4*)out, 65536);
}